// Round 7
// baseline (550.409 us; speedup 1.0000x reference)
//
#include <hip/hip_runtime.h>
#include <stdint.h>

#define IN_F  512
#define N_CTR 2048
#define BATCH 16384
#define BK    64
#define NT    (IN_F / BK)   // 8 K-tiles

using bf16x8 = __attribute__((ext_vector_type(8))) short;
using f32x4  = __attribute__((ext_vector_type(4))) float;

static __device__ __forceinline__ uint32_t f2bf(float f) {
    uint32_t u = __builtin_bit_cast(uint32_t, f);
    uint32_t r = u + 0x7fffu + ((u >> 16) & 1u);   // RNE
    return r >> 16;
}
static __device__ __forceinline__ uint32_t pack_bf2(float lo, float hi) {
    return f2bf(lo) | (f2bf(hi) << 16);
}

// Fully fused RBF kernel: reg-staged f32->bf16 MFMA GEMM + in-block norms +
// exp epilogue. One barrier per K-tile; T2 16B-slot XOR swizzle both sides.
__launch_bounds__(256, 2)
__global__ void rbf_fused(const float* __restrict__ x,
                          const float* __restrict__ cen,
                          const float* __restrict__ beta,
                          float* __restrict__ out) {
    // [buf][A=0/B=1][128 rows][64 cols bf16], rows are 128 B; 64 KiB total.
    __shared__ __align__(16) unsigned short lds[2][2][128 * 64];
    __shared__ float xsq_s[128], csq_s[128];

    const int tid  = threadIdx.x;
    const int wid  = tid >> 6;          // 0..3
    const int lane = tid & 63;
    const int wr   = wid >> 1, wc = wid & 1;
    const int g16  = lane >> 4;         // 0..3
    const int l16  = lane & 15;

    // T1: XCD chunked swizzle (bijective: 2048 % 8 == 0).
    const int bid = blockIdx.x;
    const int swz = (bid & 7) * 256 + (bid >> 3);
    const int tm  = swz >> 4;           // 0..127
    const int tn  = swz & 15;           // 0..15

    // Staging: per matrix, wave covers rows wid*32+it*4+g16, cols l16*4..+3.
    // Wave-load = 4 contiguous 256 B row segments -> fully coalesced dwordx4.
    const float* gA = x   + (size_t)(tm * 128 + wid * 32 + g16) * IN_F + l16 * 4;
    const float* gB = cen + (size_t)(tn * 128 + wid * 32 + g16) * IN_F + l16 * 4;

    float4 va[8], vb[8];
    float  xs_acc[8] = {}, cs_acc[8] = {};
    f32x4  acc[4][4] = {};

    auto issue = [&](int kt) {
        #pragma unroll
        for (int it = 0; it < 8; ++it) {
            va[it] = *reinterpret_cast<const float4*>(gA + it * 4 * IN_F + kt * BK);
            vb[it] = *reinterpret_cast<const float4*>(gB + it * 4 * IN_F + kt * BK);
        }
    };

    // vmcnt-gated (compiler-inserted) cvt + swizzled ds_write; norm accumulate.
    // Write: row r, 16B slot s=(l16>>1) -> slot s^(r&7), half (lane&1)*8.
    auto writeL = [&](int buf) {
        char* pa = (char*)&lds[buf][0][0];
        char* pb = (char*)&lds[buf][1][0];
        const int s  = l16 >> 1;
        const int hb = (lane & 1) * 8;
        #pragma unroll
        for (int it = 0; it < 8; ++it) {
            const int r  = wid * 32 + it * 4 + g16;
            const int so = ((s ^ (r & 7)) * 16) + hb;
            float4 a = va[it], b = vb[it];
            xs_acc[it] += a.x*a.x + a.y*a.y + a.z*a.z + a.w*a.w;
            cs_acc[it] += b.x*b.x + b.y*b.y + b.z*b.z + b.w*b.w;
            *reinterpret_cast<uint2*>(pa + r * 128 + so) =
                make_uint2(pack_bf2(a.x, a.y), pack_bf2(a.z, a.w));
            *reinterpret_cast<uint2*>(pb + r * 128 + so) =
                make_uint2(pack_bf2(b.x, b.y), pack_bf2(b.z, b.w));
        }
    };

    // Read: row rl, logical 16B chunk k8 = kk*4+g16 stored at slot k8^(rl&7).
    // Lanes 0..15 hit 8 distinct slots twice -> 2-way (free, m136).
    auto compute = [&](int buf) {
        const char* pa = (const char*)&lds[buf][0][0];
        const char* pb = (const char*)&lds[buf][1][0];
        bf16x8 af[4][2], bv[4][2];
        #pragma unroll
        for (int kk = 0; kk < 2; ++kk) {
            const int k8 = kk * 4 + g16;
            #pragma unroll
            for (int i = 0; i < 4; ++i) {
                const int ra = wr * 64 + i * 16 + l16;
                const int rb = wc * 64 + i * 16 + l16;
                af[i][kk] = *reinterpret_cast<const bf16x8*>(
                    pa + ra * 128 + ((k8 ^ (ra & 7)) * 16));
                bv[i][kk] = *reinterpret_cast<const bf16x8*>(
                    pb + rb * 128 + ((k8 ^ (rb & 7)) * 16));
            }
        }
        __builtin_amdgcn_s_setprio(1);
        #pragma unroll
        for (int i = 0; i < 4; ++i)
            #pragma unroll
            for (int j = 0; j < 4; ++j)
                #pragma unroll
                for (int kk = 0; kk < 2; ++kk)
                    acc[i][j] = __builtin_amdgcn_mfma_f32_16x16x32_bf16(
                        af[i][kk], bv[j][kk], acc[i][j], 0, 0, 0);
        __builtin_amdgcn_s_setprio(0);
    };

    // ---- prologue: tile 0 ----
    issue(0);
    __builtin_amdgcn_sched_barrier(0);
    writeL(0);
    __syncthreads();

    // ---- main loop: one barrier per K-tile ----
    // Race audit: writes at iter t go to buf (t+1)&1, last read at iter t-1
    // whose trailing __syncthreads() already passed (WAR ok). Reads at t+1 of
    // buf (t+1)&1 follow iter t's __syncthreads() lgkm drain (RAW ok).
    #pragma unroll
    for (int t = 0; t < NT; ++t) {
        if (t + 1 < NT) {
            issue(t + 1);                        // loads fly across compute
            __builtin_amdgcn_sched_barrier(0);   // pin issue above compute
        }
        compute(t & 1);
        __builtin_amdgcn_sched_barrier(0);       // keep cvt/vmcnt-waits below MFMAs
        if (t + 1 < NT) writeL((t + 1) & 1);
        __syncthreads();
    }

    // ---- norms: 16-lane shfl reduce, publish to LDS ----
    #pragma unroll
    for (int it = 0; it < 8; ++it) {
        float v = xs_acc[it], w = cs_acc[it];
        #pragma unroll
        for (int m = 1; m < 16; m <<= 1) {
            v += __shfl_xor(v, m);
            w += __shfl_xor(w, m);
        }
        if (l16 == 0) {
            const int r = wid * 32 + it * 4 + g16;
            xsq_s[r] = v;
            csq_s[r] = w;
        }
    }
    __syncthreads();

    // ---- epilogue: out = exp(-beta * (xsq + csq - 2*cross)) ----
    const int row0 = tm * 128 + wr * 64;
    const int col0 = tn * 128 + wc * 64;
    #pragma unroll
    for (int n = 0; n < 4; ++n) {
        const int col = col0 + n * 16 + l16;
        const float bt = beta[col];
        const float cs = csq_s[wc * 64 + n * 16 + l16];
        #pragma unroll
        for (int i = 0; i < 4; ++i) {
            #pragma unroll
            for (int j = 0; j < 4; ++j) {
                const float xs = xsq_s[wr * 64 + i * 16 + g16 * 4 + j];
                const float d  = xs + cs - 2.0f * acc[i][n][j];
                out[(size_t)(row0 + i * 16 + g16 * 4 + j) * N_CTR + col] =
                    __expf(-bt * d);
            }
        }
    }
}

extern "C" void kernel_launch(void* const* d_in, const int* in_sizes, int n_in,
                              void* d_out, int out_size, void* d_ws, size_t ws_size,
                              hipStream_t stream) {
    const float* x    = (const float*)d_in[0];
    const float* cen  = (const float*)d_in[1];
    const float* beta = (const float*)d_in[2];
    float* out        = (float*)d_out;

    rbf_fused<<<(BATCH / 128) * (N_CTR / 128), 256, 0, stream>>>(x, cen, beta, out);
}

// Round 8
// 214.258 us; speedup vs baseline: 2.5689x; 2.5689x over previous
//
#include <hip/hip_runtime.h>
#include <stdint.h>

#define IN_F  512
#define N_CTR 2048
#define BATCH 16384
#define BK    64
#define NT    (IN_F / BK)   // 8 K-tiles

using bf16x8 = __attribute__((ext_vector_type(8))) short;
using f32x4  = __attribute__((ext_vector_type(4))) float;

static __device__ __forceinline__ uint32_t f2bf(float f) {
    uint32_t u = __builtin_bit_cast(uint32_t, f);
    uint32_t r = u + 0x7fffu + ((u >> 16) & 1u);   // RNE
    return r >> 16;
}
static __device__ __forceinline__ uint32_t pack_bf2(float lo, float hi) {
    return f2bf(lo) | (f2bf(hi) << 16);
}

// Fully fused RBF kernel, 512 threads (8 waves, 2Mx4N on a 128x128 tile):
// reg-staged f32->bf16 MFMA GEMM + in-block norms + exp epilogue.
// Register budget (the R7 lesson): stage 8xfloat4=32 + acc[4][2]=32 +
// frags-per-kk=24 + norms 8 + addressing ~16 => ~112 VGPR, no spill.
__launch_bounds__(512, 2)
__global__ void rbf_fused(const float* __restrict__ x,
                          const float* __restrict__ cen,
                          const float* __restrict__ beta,
                          float* __restrict__ out) {
    // [buf][A=0/B=1][128 rows][64 cols bf16] = 64 KiB; +1 KiB norms.
    __shared__ __align__(16) unsigned short lds[2][2][128 * 64];
    __shared__ float xsq_s[128], csq_s[128];

    const int tid  = threadIdx.x;
    const int wid  = tid >> 6;          // 0..7
    const int lane = tid & 63;
    const int g16  = lane >> 4;         // 0..3
    const int l16  = lane & 15;
    const int wr   = wid >> 2;          // 0..1 (M)
    const int wc   = wid & 3;           // 0..3 (N)

    // T1: XCD chunked swizzle (bijective: 2048 % 8 == 0).
    const int bid = blockIdx.x;
    const int swz = (bid & 7) * 256 + (bid >> 3);
    const int tm  = swz >> 4;           // 0..127
    const int tn  = swz & 15;           // 0..15

    // Staging: thread covers rows it*32 + (tid>>4), f32 cols (tid&15)*4..+3.
    // 16 consecutive tids read one 64-col f32 row segment (256 B) coalesced.
    const int srow = tid >> 4;          // 0..31
    const int scol = (tid & 15) * 4;
    const float* gA = x   + (size_t)(tm * 128 + srow) * IN_F + scol;
    const float* gB = cen + (size_t)(tn * 128 + srow) * IN_F + scol;

    float4 va[4], vb[4];
    float  xs_acc[4] = {}, cs_acc[4] = {};
    f32x4  acc[4][2] = {};

    auto issue = [&](int kt) {
        #pragma unroll
        for (int it = 0; it < 4; ++it) {
            va[it] = *reinterpret_cast<const float4*>(gA + (size_t)(it * 32) * IN_F + kt * BK);
            vb[it] = *reinterpret_cast<const float4*>(gB + (size_t)(it * 32) * IN_F + kt * BK);
        }
    };

    // cvt + swizzled ds_write (8 B per matrix per it); norm accumulate.
    // Byte offset within row: (tid&15)*8 -> 16B slot s=(tid&15)>>1, half hb.
    // Swizzle slot: s ^ (row&7)  (both-sides with the read below).
    auto writeL = [&](int buf) {
        char* pa = (char*)&lds[buf][0][0];
        char* pb = (char*)&lds[buf][1][0];
        const int s  = (tid & 15) >> 1;
        const int hb = (tid & 1) * 8;
        #pragma unroll
        for (int it = 0; it < 4; ++it) {
            const int r  = it * 32 + srow;
            const int so = ((s ^ (r & 7)) << 4) + hb;
            float4 a = va[it], b = vb[it];
            xs_acc[it] += a.x*a.x + a.y*a.y + a.z*a.z + a.w*a.w;
            cs_acc[it] += b.x*b.x + b.y*b.y + b.z*b.z + b.w*b.w;
            *reinterpret_cast<uint2*>(pa + r * 128 + so) =
                make_uint2(pack_bf2(a.x, a.y), pack_bf2(a.z, a.w));
            *reinterpret_cast<uint2*>(pb + r * 128 + so) =
                make_uint2(pack_bf2(b.x, b.y), pack_bf2(b.z, b.w));
        }
    };

    // Read: row rl, logical 16B chunk k8=kk*4+g16 stored at slot k8^(rl&7).
    // 16-lane group hits 8 distinct slots twice -> 2-way (free, m136).
    auto compute = [&](int buf) {
        const char* pa = (const char*)&lds[buf][0][0];
        const char* pb = (const char*)&lds[buf][1][0];
        #pragma unroll
        for (int kk = 0; kk < 2; ++kk) {
            const int k8 = kk * 4 + g16;
            bf16x8 af[4], bv[2];
            #pragma unroll
            for (int i = 0; i < 4; ++i) {
                const int ra = wr * 64 + i * 16 + l16;
                af[i] = *reinterpret_cast<const bf16x8*>(
                    pa + ra * 128 + ((k8 ^ (ra & 7)) << 4));
            }
            #pragma unroll
            for (int n = 0; n < 2; ++n) {
                const int rb = wc * 32 + n * 16 + l16;
                bv[n] = *reinterpret_cast<const bf16x8*>(
                    pb + rb * 128 + ((k8 ^ (rb & 7)) << 4));
            }
            __builtin_amdgcn_s_setprio(1);
            #pragma unroll
            for (int i = 0; i < 4; ++i)
                #pragma unroll
                for (int n = 0; n < 2; ++n)
                    acc[i][n] = __builtin_amdgcn_mfma_f32_16x16x32_bf16(
                        af[i], bv[n], acc[i][n], 0, 0, 0);
            __builtin_amdgcn_s_setprio(0);
        }
    };

    // ---- prologue: tile 0 ----
    issue(0);
    writeL(0);
    __syncthreads();

    // ---- main loop: one barrier per K-tile (T14: issue early, write late) ----
    // Race audit: writeL at iter t targets buf (t+1)&1, last read by compute
    // at t-1 (barrier at end of t-1 between). Reads of buf (t+1)&1 at t+1
    // follow iter t's __syncthreads lgkm drain.
    #pragma unroll
    for (int t = 0; t < NT; ++t) {
        if (t + 1 < NT) {
            issue(t + 1);                        // loads fly across compute
            __builtin_amdgcn_sched_barrier(0);   // don't sink loads below MFMAs
        }
        compute(t & 1);
        __builtin_amdgcn_sched_barrier(0);       // keep vmcnt-wait/cvt below MFMAs
        if (t + 1 < NT) writeL((t + 1) & 1);
        __syncthreads();
    }

    // ---- norms: 16-lane shfl reduce, publish to LDS ----
    #pragma unroll
    for (int it = 0; it < 4; ++it) {
        float v = xs_acc[it], w = cs_acc[it];
        #pragma unroll
        for (int m = 1; m < 16; m <<= 1) {
            v += __shfl_xor(v, m);
            w += __shfl_xor(w, m);
        }
        if (l16 == 0) {
            const int r = it * 32 + srow;        // srow = wid*4 + g16
            xsq_s[r] = v;
            csq_s[r] = w;
        }
    }
    __syncthreads();

    // ---- epilogue: out = exp(-beta * (xsq + csq - 2*cross)) ----
    const int row_base = tm * 128;
    #pragma unroll
    for (int n = 0; n < 2; ++n) {
        const int col = tn * 128 + wc * 32 + n * 16 + l16;
        const float bt = beta[col];
        const float cs = csq_s[wc * 32 + n * 16 + l16];
        #pragma unroll
        for (int i = 0; i < 4; ++i) {
            #pragma unroll
            for (int j = 0; j < 4; ++j) {
                const int ro = wr * 64 + i * 16 + g16 * 4 + j;
                const float d = xsq_s[ro] + cs - 2.0f * acc[i][n][j];
                out[(size_t)(row_base + ro) * N_CTR + col] = __expf(-bt * d);
            }
        }
    }
}

extern "C" void kernel_launch(void* const* d_in, const int* in_sizes, int n_in,
                              void* d_out, int out_size, void* d_ws, size_t ws_size,
                              hipStream_t stream) {
    const float* x    = (const float*)d_in[0];
    const float* cen  = (const float*)d_in[1];
    const float* beta = (const float*)d_in[2];
    float* out        = (float*)d_out;

    rbf_fused<<<(BATCH / 128) * (N_CTR / 128), 512, 0, stream>>>(x, cen, beta, out);
}

// Round 9
// 172.290 us; speedup vs baseline: 3.1947x; 1.2436x over previous
//
#include <hip/hip_runtime.h>
#include <hip/hip_bf16.h>
#include <stdint.h>

#define IN_F  512
#define N_CTR 2048
#define BATCH 16384
#define BK    64
#define NT    (IN_F / BK)   // 8 K-tiles

using bf16x8 = __attribute__((ext_vector_type(8))) short;
using f32x4  = __attribute__((ext_vector_type(4))) float;

// Pack 2 f32 -> 1 u32 of 2 bf16 (RNE). __float22bfloat162_rn compiles to
// v_cvt_pk_bf16_f32 on gfx950; memcpy sidesteps non-trivially-copyable
// __hip_bfloat162 (R6 compile failure).
static __device__ __forceinline__ uint32_t pack_bf2(float lo, float hi) {
    __hip_bfloat162 h = __float22bfloat162_rn(float2{lo, hi});
    uint32_t u;
    __builtin_memcpy(&u, &h, 4);
    return u;
}

// Fully fused RBF kernel, 512 threads (8 waves, 2Mx4N on a 128x128 tile):
// reg-staged f32->bf16 MFMA GEMM + in-block norms + exp epilogue.
// R8 lesson: live set ~150 VGPR; do NOT cap the allocator below that
// (launch_bounds(512,2) forced 128 -> 590 MB scratch traffic).
__launch_bounds__(512)
__global__ void rbf_fused(const float* __restrict__ x,
                          const float* __restrict__ cen,
                          const float* __restrict__ beta,
                          float* __restrict__ out) {
    // [buf][A=0/B=1][128 rows][64 cols bf16] = 64 KiB; +1 KiB norms.
    __shared__ __align__(16) unsigned short lds[2][2][128 * 64];
    __shared__ float xsq_s[128], csq_s[128];

    const int tid  = threadIdx.x;
    const int wid  = tid >> 6;          // 0..7
    const int lane = tid & 63;
    const int g16  = lane >> 4;         // 0..3
    const int l16  = lane & 15;
    const int wr   = wid >> 2;          // 0..1 (M)
    const int wc   = wid & 3;           // 0..3 (N)

    // T1: XCD chunked swizzle (bijective: 2048 % 8 == 0).
    const int bid = blockIdx.x;
    const int swz = (bid & 7) * 256 + (bid >> 3);
    const int tm  = swz >> 4;           // 0..127
    const int tn  = swz & 15;           // 0..15

    // Staging: thread covers rows it*32 + (tid>>4), f32 cols (tid&15)*4..+3.
    // 16 consecutive tids read one 64-col f32 row segment (256 B) coalesced.
    const int srow = tid >> 4;          // 0..31
    const int scol = (tid & 15) * 4;
    const float* gA = x   + (size_t)(tm * 128 + srow) * IN_F + scol;
    const float* gB = cen + (size_t)(tn * 128 + srow) * IN_F + scol;

    float4 va[4], vb[4];
    float  xs_acc[4] = {}, cs_acc[4] = {};
    f32x4  acc[4][2] = {};

    auto issue = [&](int kt) {
        #pragma unroll
        for (int it = 0; it < 4; ++it) {
            va[it] = *reinterpret_cast<const float4*>(gA + (size_t)(it * 32) * IN_F + kt * BK);
            vb[it] = *reinterpret_cast<const float4*>(gB + (size_t)(it * 32) * IN_F + kt * BK);
        }
    };

    // cvt_pk + swizzled ds_write (8 B per matrix per it); norm accumulate.
    // Byte offset within row: (tid&15)*8 -> 16B slot s=(tid&15)>>1, half hb.
    // Swizzle slot: s ^ (row&7)  (both-sides with the read below).
    auto writeL = [&](int buf) {
        char* pa = (char*)&lds[buf][0][0];
        char* pb = (char*)&lds[buf][1][0];
        const int s  = (tid & 15) >> 1;
        const int hb = (tid & 1) * 8;
        #pragma unroll
        for (int it = 0; it < 4; ++it) {
            const int r  = it * 32 + srow;
            const int so = ((s ^ (r & 7)) << 4) + hb;
            float4 a = va[it], b = vb[it];
            xs_acc[it] += a.x*a.x + a.y*a.y + a.z*a.z + a.w*a.w;
            cs_acc[it] += b.x*b.x + b.y*b.y + b.z*b.z + b.w*b.w;
            *reinterpret_cast<uint2*>(pa + r * 128 + so) =
                make_uint2(pack_bf2(a.x, a.y), pack_bf2(a.z, a.w));
            *reinterpret_cast<uint2*>(pb + r * 128 + so) =
                make_uint2(pack_bf2(b.x, b.y), pack_bf2(b.z, b.w));
        }
    };

    // Read: row rl, logical 16B chunk k8=kk*4+g16 stored at slot k8^(rl&7).
    // 16-lane group hits 8 distinct slots twice -> 2-way (free, m136).
    auto compute = [&](int buf) {
        const char* pa = (const char*)&lds[buf][0][0];
        const char* pb = (const char*)&lds[buf][1][0];
        #pragma unroll
        for (int kk = 0; kk < 2; ++kk) {
            const int k8 = kk * 4 + g16;
            bf16x8 af[4], bv[2];
            #pragma unroll
            for (int i = 0; i < 4; ++i) {
                const int ra = wr * 64 + i * 16 + l16;
                af[i] = *reinterpret_cast<const bf16x8*>(
                    pa + ra * 128 + ((k8 ^ (ra & 7)) << 4));
            }
            #pragma unroll
            for (int n = 0; n < 2; ++n) {
                const int rb = wc * 32 + n * 16 + l16;
                bv[n] = *reinterpret_cast<const bf16x8*>(
                    pb + rb * 128 + ((k8 ^ (rb & 7)) << 4));
            }
            __builtin_amdgcn_s_setprio(1);
            #pragma unroll
            for (int i = 0; i < 4; ++i)
                #pragma unroll
                for (int n = 0; n < 2; ++n)
                    acc[i][n] = __builtin_amdgcn_mfma_f32_16x16x32_bf16(
                        af[i], bv[n], acc[i][n], 0, 0, 0);
            __builtin_amdgcn_s_setprio(0);
        }
    };

    // ---- prologue: tile 0 ----
    issue(0);
    writeL(0);
    __syncthreads();

    // ---- main loop: one barrier per K-tile (T14: issue early, write late) ----
    // Race audit: writeL at iter t targets buf (t+1)&1, last read by compute
    // at t-1 (barrier at end of t-1 between). Reads of buf (t+1)&1 at t+1
    // follow iter t's __syncthreads lgkm drain.
    #pragma unroll
    for (int t = 0; t < NT; ++t) {
        if (t + 1 < NT) {
            issue(t + 1);                        // loads fly across compute
            __builtin_amdgcn_sched_barrier(0);   // don't sink loads below MFMAs
        }
        compute(t & 1);
        __builtin_amdgcn_sched_barrier(0);       // keep vmcnt-wait/cvt below MFMAs
        if (t + 1 < NT) writeL((t + 1) & 1);
        __syncthreads();
    }

    // ---- norms: 16-lane shfl reduce, publish to LDS ----
    #pragma unroll
    for (int it = 0; it < 4; ++it) {
        float v = xs_acc[it], w = cs_acc[it];
        #pragma unroll
        for (int m = 1; m < 16; m <<= 1) {
            v += __shfl_xor(v, m);
            w += __shfl_xor(w, m);
        }
        if (l16 == 0) {
            const int r = it * 32 + srow;
            xsq_s[r] = v;
            csq_s[r] = w;
        }
    }
    __syncthreads();

    // ---- epilogue: out = exp(-beta * (xsq + csq - 2*cross)) ----
    const int row_base = tm * 128;
    #pragma unroll
    for (int n = 0; n < 2; ++n) {
        const int col = tn * 128 + wc * 32 + n * 16 + l16;
        const float bt = beta[col];
        const float cs = csq_s[wc * 32 + n * 16 + l16];
        #pragma unroll
        for (int i = 0; i < 4; ++i) {
            #pragma unroll
            for (int j = 0; j < 4; ++j) {
                const int ro = wr * 64 + i * 16 + g16 * 4 + j;
                const float d = xsq_s[ro] + cs - 2.0f * acc[i][n][j];
                out[(size_t)(row_base + ro) * N_CTR + col] = __expf(-bt * d);
            }
        }
    }
}

extern "C" void kernel_launch(void* const* d_in, const int* in_sizes, int n_in,
                              void* d_out, int out_size, void* d_ws, size_t ws_size,
                              hipStream_t stream) {
    const float* x    = (const float*)d_in[0];
    const float* cen  = (const float*)d_in[1];
    const float* beta = (const float*)d_in[2];
    float* out        = (float*)d_out;

    rbf_fused<<<(BATCH / 128) * (N_CTR / 128), 512, 0, stream>>>(x, cen, beta, out);
}

// Round 10
// 170.013 us; speedup vs baseline: 3.2375x; 1.0134x over previous
//
#include <hip/hip_runtime.h>
#include <hip/hip_bf16.h>
#include <stdint.h>

#define IN_F  512
#define N_CTR 2048
#define BATCH 16384
#define BK    64
#define NT    (IN_F / BK)   // 8 K-tiles

using bf16x8 = __attribute__((ext_vector_type(8))) short;
using f32x4  = __attribute__((ext_vector_type(4))) float;

// Pack 2 f32 -> 1 u32 of 2 bf16 (RNE): v_cvt_pk_bf16_f32 on gfx950.
static __device__ __forceinline__ uint32_t pack_bf2(float lo, float hi) {
    __hip_bfloat162 h = __float22bfloat162_rn(float2{lo, hi});
    uint32_t u;
    __builtin_memcpy(&u, &h, 4);
    return u;
}

// Fully fused RBF kernel, 512 threads (8 waves, 2Mx4N on a 128x128 tile):
// reg-staged f32->bf16 MFMA GEMM + in-block norms + exp epilogue.
// R9 lesson: the backend spills to hit LDS-implied occupancy (4 waves/SIMD
// => 128 VGPR cap). launch_bounds(512, 1) sets amdgpu-waves-per-eu min=1,
// releasing the allocator to ~256 so the ~160-reg live set fits spill-free.
__launch_bounds__(512, 1)
__global__ void rbf_fused(const float* __restrict__ x,
                          const float* __restrict__ cen,
                          const float* __restrict__ beta,
                          float* __restrict__ out) {
    // [buf][A=0/B=1][128 rows][64 cols bf16] = 64 KiB; +1 KiB norms.
    __shared__ __align__(16) unsigned short lds[2][2][128 * 64];
    __shared__ float xsq_s[128], csq_s[128];

    const int tid  = threadIdx.x;
    const int wid  = tid >> 6;          // 0..7
    const int lane = tid & 63;
    const int g16  = lane >> 4;         // 0..3
    const int l16  = lane & 15;
    const int wr   = wid >> 2;          // 0..1 (M)
    const int wc   = wid & 3;           // 0..3 (N)

    // T1: XCD chunked swizzle (bijective: 2048 % 8 == 0).
    const int bid = blockIdx.x;
    const int swz = (bid & 7) * 256 + (bid >> 3);
    const int tm  = swz >> 4;           // 0..127
    const int tn  = swz & 15;           // 0..15

    // Staging: thread covers rows it*32 + (tid>>4), f32 cols (tid&15)*4..+3.
    // 16 consecutive tids read one 64-col f32 row segment (256 B) coalesced.
    const int srow = tid >> 4;          // 0..31
    const int scol = (tid & 15) * 4;
    const float* gA = x   + (size_t)(tm * 128 + srow) * IN_F + scol;
    const float* gB = cen + (size_t)(tn * 128 + srow) * IN_F + scol;

    float4 va[4], vb[4];
    float  xs_acc[4] = {}, cs_acc[4] = {};
    f32x4  acc[4][2] = {};

    auto issue = [&](int kt) {
        #pragma unroll
        for (int it = 0; it < 4; ++it) {
            va[it] = *reinterpret_cast<const float4*>(gA + (size_t)(it * 32) * IN_F + kt * BK);
            vb[it] = *reinterpret_cast<const float4*>(gB + (size_t)(it * 32) * IN_F + kt * BK);
        }
    };

    // cvt_pk + swizzled ds_write (8 B per matrix per it); norm accumulate.
    // Byte offset within row: (tid&15)*8 -> 16B slot s=(tid&15)>>1, half hb.
    // Swizzle slot: s ^ (row&7)  (both-sides with the read below).
    auto writeL = [&](int buf) {
        char* pa = (char*)&lds[buf][0][0];
        char* pb = (char*)&lds[buf][1][0];
        const int s  = (tid & 15) >> 1;
        const int hb = (tid & 1) * 8;
        #pragma unroll
        for (int it = 0; it < 4; ++it) {
            const int r  = it * 32 + srow;
            const int so = ((s ^ (r & 7)) << 4) + hb;
            float4 a = va[it], b = vb[it];
            xs_acc[it] += a.x*a.x + a.y*a.y + a.z*a.z + a.w*a.w;
            cs_acc[it] += b.x*b.x + b.y*b.y + b.z*b.z + b.w*b.w;
            *reinterpret_cast<uint2*>(pa + r * 128 + so) =
                make_uint2(pack_bf2(a.x, a.y), pack_bf2(a.z, a.w));
            *reinterpret_cast<uint2*>(pb + r * 128 + so) =
                make_uint2(pack_bf2(b.x, b.y), pack_bf2(b.z, b.w));
        }
    };

    // Read: row rl, logical 16B chunk k8=kk*4+g16 stored at slot k8^(rl&7).
    // 16-lane group hits 8 distinct slots twice -> 2-way (free, m136).
    auto compute = [&](int buf) {
        const char* pa = (const char*)&lds[buf][0][0];
        const char* pb = (const char*)&lds[buf][1][0];
        #pragma unroll
        for (int kk = 0; kk < 2; ++kk) {
            const int k8 = kk * 4 + g16;
            bf16x8 af[4], bv[2];
            #pragma unroll
            for (int i = 0; i < 4; ++i) {
                const int ra = wr * 64 + i * 16 + l16;
                af[i] = *reinterpret_cast<const bf16x8*>(
                    pa + ra * 128 + ((k8 ^ (ra & 7)) << 4));
            }
            #pragma unroll
            for (int n = 0; n < 2; ++n) {
                const int rb = wc * 32 + n * 16 + l16;
                bv[n] = *reinterpret_cast<const bf16x8*>(
                    pb + rb * 128 + ((k8 ^ (rb & 7)) << 4));
            }
            __builtin_amdgcn_s_setprio(1);
            #pragma unroll
            for (int i = 0; i < 4; ++i)
                #pragma unroll
                for (int n = 0; n < 2; ++n)
                    acc[i][n] = __builtin_amdgcn_mfma_f32_16x16x32_bf16(
                        af[i], bv[n], acc[i][n], 0, 0, 0);
            __builtin_amdgcn_s_setprio(0);
        }
    };

    // ---- prologue: tile 0 ----
    issue(0);
    writeL(0);
    __syncthreads();

    // ---- main loop: one barrier per K-tile (T14: issue early, write late) ----
    // Race audit: writeL at iter t targets buf (t+1)&1, last read by compute
    // at t-1 (barrier at end of t-1 between). Reads of buf (t+1)&1 at t+1
    // follow iter t's __syncthreads lgkm drain.
    #pragma unroll
    for (int t = 0; t < NT; ++t) {
        if (t + 1 < NT) {
            issue(t + 1);                        // loads fly across compute
            __builtin_amdgcn_sched_barrier(0);   // don't sink loads below MFMAs
        }
        compute(t & 1);
        __builtin_amdgcn_sched_barrier(0);       // keep vmcnt-wait/cvt below MFMAs
        if (t + 1 < NT) writeL((t + 1) & 1);
        __syncthreads();
    }

    // ---- norms: 16-lane shfl reduce, publish to LDS ----
    #pragma unroll
    for (int it = 0; it < 4; ++it) {
        float v = xs_acc[it], w = cs_acc[it];
        #pragma unroll
        for (int m = 1; m < 16; m <<= 1) {
            v += __shfl_xor(v, m);
            w += __shfl_xor(w, m);
        }
        if (l16 == 0) {
            const int r = it * 32 + srow;
            xsq_s[r] = v;
            csq_s[r] = w;
        }
    }
    __syncthreads();

    // ---- epilogue: out = exp(-beta * (xsq + csq - 2*cross)) ----
    const int row_base = tm * 128;
    #pragma unroll
    for (int n = 0; n < 2; ++n) {
        const int col = tn * 128 + wc * 32 + n * 16 + l16;
        const float bt = beta[col];
        const float cs = csq_s[wc * 32 + n * 16 + l16];
        #pragma unroll
        for (int i = 0; i < 4; ++i) {
            #pragma unroll
            for (int j = 0; j < 4; ++j) {
                const int ro = wr * 64 + i * 16 + g16 * 4 + j;
                const float d = xsq_s[ro] + cs - 2.0f * acc[i][n][j];
                out[(size_t)(row_base + ro) * N_CTR + col] = __expf(-bt * d);
            }
        }
    }
}

extern "C" void kernel_launch(void* const* d_in, const int* in_sizes, int n_in,
                              void* d_out, int out_size, void* d_ws, size_t ws_size,
                              hipStream_t stream) {
    const float* x    = (const float*)d_in[0];
    const float* cen  = (const float*)d_in[1];
    const float* beta = (const float*)d_in[2];
    float* out        = (float*)d_out;

    rbf_fused<<<(BATCH / 128) * (N_CTR / 128), 512, 0, stream>>>(x, cen, beta, out);
}

// Round 11
// 90.752 us; speedup vs baseline: 6.0650x; 1.8734x over previous
//
#include <hip/hip_runtime.h>
#include <stdint.h>

#define IN_F   512
#define N_CTR  2048
#define BATCH  16384
#define BK     64
#define NKT    (IN_F / BK)   // 8

#define BM 256   // rows per block = 8 waves x 32
#define BN 64    // cols per block = B-tile rows

using bf16x8  = __attribute__((ext_vector_type(8))) short;
using f32x4   = __attribute__((ext_vector_type(4))) float;
using ushort8 = __attribute__((ext_vector_type(8))) unsigned short;

typedef const __attribute__((address_space(1))) void* gptr_t;
typedef __attribute__((address_space(3))) void* lptr_t;

static __device__ __forceinline__ unsigned short f2bf(float f) {
    uint32_t u = __builtin_bit_cast(uint32_t, f);
    uint32_t r = u + 0x7fffu + ((u >> 16) & 1u);   // RNE
    return (unsigned short)(r >> 16);
}

// Merged converter (proven R1): one wave per row across BOTH x and centers.
// f32 row -> bf16 row in ws, plus exact-f32 sum of squares.
__global__ void convert_all(const float* __restrict__ x,
                            const float* __restrict__ c,
                            unsigned short* __restrict__ xb,
                            unsigned short* __restrict__ cb,
                            float* __restrict__ xsq,
                            float* __restrict__ csq) {
    const int wave = threadIdx.x >> 6;
    const int lane = threadIdx.x & 63;
    const int row  = blockIdx.x * 4 + wave;

    const float* src;
    unsigned short* dst;
    float* sq;
    int r;
    if (row < BATCH) { src = x; dst = xb; sq = xsq; r = row; }
    else             { src = c; dst = cb; sq = csq; r = row - BATCH; }

    const float* rp = src + (size_t)r * IN_F + lane * 8;
    float4 a = *reinterpret_cast<const float4*>(rp);
    float4 b = *reinterpret_cast<const float4*>(rp + 4);
    float ss = a.x*a.x + a.y*a.y + a.z*a.z + a.w*a.w
             + b.x*b.x + b.y*b.y + b.z*b.z + b.w*b.w;
    ushort8 o;
    o[0]=f2bf(a.x); o[1]=f2bf(a.y); o[2]=f2bf(a.z); o[3]=f2bf(a.w);
    o[4]=f2bf(b.x); o[5]=f2bf(b.y); o[6]=f2bf(b.z); o[7]=f2bf(b.w);
    *reinterpret_cast<ushort8*>(dst + (size_t)r * IN_F + lane * 8) = o;
    #pragma unroll
    for (int off = 32; off > 0; off >>= 1) ss += __shfl_down(ss, off);
    if (lane == 0) sq[r] = ss;
}

// B-stationary / A-streaming RBF GEMM:
//  - B tile (BN x full-K bf16 = 64 KB) staged to LDS ONCE (XOR-swizzled
//    source, rule 21), single __syncthreads in the whole kernel.
//  - Each wave owns 32 A-rows; A fragments stream global->reg (bf16),
//    register-double-buffered via manual unroll-2 (static names, rule 20).
//  - No loop barriers: the 2-phase stage+drain ceiling (m233) cannot apply.
//  VGPR budget ~105 (acc 32 + afA/afB 32 + bfr 16 + addr ~20) < 128 pin.
__launch_bounds__(512)
__global__ void rbf_gemm_stream(const unsigned short* __restrict__ xb,
                                const unsigned short* __restrict__ cb,
                                const float* __restrict__ xsq,
                                const float* __restrict__ csq,
                                const float* __restrict__ beta,
                                float* __restrict__ out) {
    __shared__ __align__(16) unsigned short Bs[BN * IN_F];   // 64 KiB

    const int tid  = threadIdx.x;
    const int wid  = tid >> 6;          // 0..7
    const int lane = tid & 63;
    const int g16  = lane >> 4;         // 0..3
    const int l16  = lane & 15;

    // T1 XCD chunked swizzle (bijective: 2048 % 8 == 0). tn fastest so each
    // XCD chunk re-reads a 2 MB A-panel against the L2-resident B.
    const int bid  = blockIdx.x;
    const int swzc = (bid & 7) * 256 + (bid >> 3);
    const int tm   = swzc >> 5;         // 0..63
    const int tn   = swzc & 31;         // 0..31

    // ---- stage B tile once: row r linear in LDS, source chunk lane^(r&7) ----
    #pragma unroll
    for (int rr = 0; rr < 8; ++rr) {
        const int r = wid * 8 + rr;     // r&7 == rr
        const unsigned short* src = cb + (size_t)(tn * BN + r) * IN_F + (lane ^ rr) * 8;
        __builtin_amdgcn_global_load_lds((gptr_t)src, (lptr_t)(Bs + r * IN_F), 16, 0, 0);
    }

    const int arow0 = tm * BM + wid * 32;
    const unsigned short* gA = xb + (size_t)(arow0 + l16) * IN_F + g16 * 8;

    f32x4  acc[2][4] = {};
    bf16x8 afA[2][2], afB[2][2];

    auto loadA = [&](bf16x8 dst[2][2], int kt) {
        #pragma unroll
        for (int i = 0; i < 2; ++i)
            #pragma unroll
            for (int kk = 0; kk < 2; ++kk)
                dst[i][kk] = *reinterpret_cast<const bf16x8*>(
                    gA + (size_t)(i * 16) * IN_F + kt * BK + kk * 32);
    };

    auto computeKT = [&](bf16x8 af[2][2], int kt) {
        #pragma unroll
        for (int kk = 0; kk < 2; ++kk) {
            bf16x8 bfr[4];
            #pragma unroll
            for (int ni = 0; ni < 4; ++ni) {
                const int rb   = ni * 16 + l16;                   // B row 0..63
                const int slot = kt * 8 + ((kk * 4 + g16) ^ (rb & 7));
                bfr[ni] = *reinterpret_cast<const bf16x8*>(
                    (const char*)Bs + rb * (IN_F * 2) + slot * 16);
            }
            #pragma unroll
            for (int i = 0; i < 2; ++i)
                #pragma unroll
                for (int ni = 0; ni < 4; ++ni)
                    acc[i][ni] = __builtin_amdgcn_mfma_f32_16x16x32_bf16(
                        af[i][kk], bfr[ni], acc[i][ni], 0, 0, 0);
        }
    };

    loadA(afA, 0);
    __syncthreads();                    // B visible; also drains afA (harmless)

    // ---- barrier-free main loop, reg-double-buffered A (unroll-2, static) ----
    #pragma unroll 1
    for (int kt = 0; kt < NKT; kt += 2) {
        loadA(afB, kt + 1);             // kt+1 <= 7 always (NKT even)
        computeKT(afA, kt);
        if (kt + 2 < NKT) loadA(afA, kt + 2);
        computeKT(afB, kt + 1);
    }

    // ---- epilogue: out = exp(-beta * (xsq + csq - 2*cross)) ----
    const int colb = tn * BN;
    float csb[4], btb[4];
    #pragma unroll
    for (int ni = 0; ni < 4; ++ni) {
        const int col = colb + ni * 16 + l16;
        csb[ni] = csq[col];
        btb[ni] = beta[col];
    }
    #pragma unroll
    for (int i = 0; i < 2; ++i) {
        #pragma unroll
        for (int j = 0; j < 4; ++j) {
            const int row = arow0 + i * 16 + g16 * 4 + j;   // C/D: row=(lane>>4)*4+reg
            const float xs = xsq[row];
            float* op = out + (size_t)row * N_CTR + colb;
            #pragma unroll
            for (int ni = 0; ni < 4; ++ni)
                op[ni * 16 + l16] = __expf(-btb[ni] * (xs + csb[ni] - 2.0f * acc[i][ni][j]));
        }
    }
}

// Fallback (ws too small): correct f32 path, LDS-staged x row.
__global__ void rbf_naive(const float* __restrict__ x,
                          const float* __restrict__ c,
                          const float* __restrict__ beta,
                          float* __restrict__ out) {
    __shared__ float xs[IN_F];
    const int row = blockIdx.x;
    const int col = blockIdx.y * 128 + threadIdx.x;
    for (int i = threadIdx.x; i < IN_F; i += 128)
        xs[i] = x[(size_t)row * IN_F + i];
    __syncthreads();
    const float* cp = c + (size_t)col * IN_F;
    float d = 0.f;
    #pragma unroll 4
    for (int k = 0; k < IN_F; k += 4) {
        float4 cv = *reinterpret_cast<const float4*>(cp + k);
        float t0 = xs[k + 0] - cv.x;
        float t1 = xs[k + 1] - cv.y;
        float t2 = xs[k + 2] - cv.z;
        float t3 = xs[k + 3] - cv.w;
        d += t0 * t0 + t1 * t1 + t2 * t2 + t3 * t3;
    }
    out[(size_t)row * N_CTR + col] = __expf(-beta[col] * d);
}

extern "C" void kernel_launch(void* const* d_in, const int* in_sizes, int n_in,
                              void* d_out, int out_size, void* d_ws, size_t ws_size,
                              hipStream_t stream) {
    const float* x    = (const float*)d_in[0];
    const float* c    = (const float*)d_in[1];
    const float* beta = (const float*)d_in[2];
    float* out        = (float*)d_out;

    const size_t need = (size_t)BATCH * IN_F * 2 + (size_t)N_CTR * IN_F * 2
                      + (size_t)BATCH * 4 + (size_t)N_CTR * 4;
    if (ws_size >= need) {
        unsigned short* xbuf = (unsigned short*)d_ws;
        unsigned short* cbuf = xbuf + (size_t)BATCH * IN_F;
        float* xsq = (float*)(cbuf + (size_t)N_CTR * IN_F);
        float* csq = xsq + BATCH;
        convert_all<<<(BATCH + N_CTR) / 4, 256, 0, stream>>>(x, c, xbuf, cbuf, xsq, csq);
        rbf_gemm_stream<<<(BATCH / BM) * (N_CTR / BN), 512, 0, stream>>>(
            xbuf, cbuf, xsq, csq, beta, out);
    } else {
        rbf_naive<<<dim3(BATCH, N_CTR / 128), 128, 0, stream>>>(x, c, beta, out);
    }
}